// Round 5
// baseline (225.334 us; speedup 1.0000x reference)
//
#include <hip/hip_runtime.h>

#define NN 8192
#define DD 256
#define JSPLIT 2
#define JCH (NN / JSPLIT)          // 4096 j's per block
#define NSTEP (JCH / 32)           // 128 K-steps per block

typedef __attribute__((ext_vector_type(8))) short short8;   // 8 bf16 (4 VGPR) MFMA frag
typedef __attribute__((ext_vector_type(4))) float f32x4;    // MFMA accumulator

__device__ __forceinline__ short f2bf(float x) {
    union { float f; unsigned u; } v; v.f = x;
    unsigned r = (v.u + 0x7FFFu + ((v.u >> 16) & 1u)) >> 16;  // RNE
    return (short)r;
}
__device__ __forceinline__ float bf2f(short b) {
    union { float f; unsigned u; } v; v.u = ((unsigned)(unsigned short)b) << 16;
    return v.f;
}

// Barrier that does NOT drain vmcnt (in-flight global prefetch survives).
__device__ __forceinline__ void barrier_keep_vmem() {
    asm volatile("s_waitcnt lgkmcnt(0)" ::: "memory");
    __builtin_amdgcn_s_barrier();
    asm volatile("" ::: "memory");
}

// Kernel 1: h = x@W (fp32); emit hT (bf16, [D][N]), e_src, e_dst.
__global__ __launch_bounds__(256) void gat_prep(
    const float* __restrict__ x, const float* __restrict__ W,
    const float* __restrict__ a,
    short* __restrict__ hT, float* __restrict__ e_src, float* __restrict__ e_dst)
{
    __shared__ float x_s[32][260];          // +4 pad
    __shared__ float W_s[2][16][256];       // 16-row W chunk, double-buffered
    const int t  = threadIdx.x;
    const int ib = blockIdx.x * 32;

    #pragma unroll
    for (int rep = 0; rep < 8; ++rep) {
        int fi = rep * 256 + t;
        int r  = fi >> 6;
        int c4 = (fi & 63) * 4;
        float4 v = *(const float4*)(x + (size_t)(ib + r) * DD + c4);
        *(float4*)&x_s[r][c4] = v;
    }
    float4 wp[4];
    #pragma unroll
    for (int q = 0; q < 4; ++q) {
        int fi = q * 256 + t;
        wp[q] = *(const float4*)(W + (size_t)(fi >> 6) * DD + (fi & 63) * 4);
    }
    barrier_keep_vmem();

    const int il = t >> 3;
    const int dg = (t & 7) * 4;
    f32x4 acc[8];
    #pragma unroll
    for (int m = 0; m < 8; ++m) acc[m] = (f32x4){0.f, 0.f, 0.f, 0.f};

    for (int kc = 0; kc < 16; ++kc) {
        const int b = kc & 1;
        #pragma unroll
        for (int q = 0; q < 4; ++q) {
            int fi = q * 256 + t;
            *(float4*)&W_s[b][fi >> 6][(fi & 63) * 4] = wp[q];
        }
        if (kc < 15) {
            #pragma unroll
            for (int q = 0; q < 4; ++q) {
                int fi = q * 256 + t;
                wp[q] = *(const float4*)(W + (size_t)((kc + 1) * 16 + (fi >> 6)) * DD + (fi & 63) * 4);
            }
        }
        barrier_keep_vmem();
        #pragma unroll
        for (int kl = 0; kl < 16; ++kl) {
            float xv = x_s[il][kc * 16 + kl];
            #pragma unroll
            for (int m = 0; m < 8; ++m) {
                float4 wv = *(const float4*)&W_s[b][kl][m * 32 + dg];
                acc[m].x += xv * wv.x; acc[m].y += xv * wv.y;
                acc[m].z += xv * wv.z; acc[m].w += xv * wv.w;
            }
        }
    }

    const int ig = ib + il;
    float p1 = 0.f, p2 = 0.f;
    #pragma unroll
    for (int m = 0; m < 8; ++m) {
        #pragma unroll
        for (int j = 0; j < 4; ++j) {
            int col = m * 32 + dg + j;
            float hv = acc[m][j];
            p1 += hv * a[col];
            p2 += hv * a[DD + col];
            hT[(size_t)col * NN + ig] = f2bf(hv);
        }
    }
    p1 += __shfl_xor(p1, 1); p1 += __shfl_xor(p1, 2); p1 += __shfl_xor(p1, 4);
    p2 += __shfl_xor(p2, 1); p2 += __shfl_xor(p2, 2); p2 += __shfl_xor(p2, 4);
    if ((t & 7) == 0) { e_src[ig] = p1; e_dst[ig] = p2; }
}

// Kernel 2: fused masked softmax-numerator GEMM.
// v4: B (hT fragments) loaded global->register directly (L2-resident; the
// 4 j-offset lane groups cover the same 16 cache lines -> coalesces to full
// lines). LDS keeps only the 5KB double-buffered weight tile w_s. Wave w
// owns cols [w*32, w*32+32), computes BOTH row halves: acc[2][2], 4 MFMAs.
__global__ __launch_bounds__(512, 4) void gat_main(
    const int* __restrict__ adj, const short* __restrict__ hT,
    const float* __restrict__ e_src, const float* __restrict__ e_dst,
    float* __restrict__ num0, float* __restrict__ num1,
    float* __restrict__ den_part)
{
    __shared__ __align__(16) short w_s[2][32][40];    // weight tile bf16 (only LDS)

    const int t    = threadIdx.x;
    const int lane = t & 63;
    const int wid  = t >> 6;
    const int ibl  = (blockIdx.x >> 1) * 32;
    const int half = blockIdx.x & 1;
    const int jb   = half * JCH;

    const int irow = t >> 4;                  // 0..31 (weight-builder row)
    const int jc2  = (t & 15) * 2;
    const float es = e_src[ibl + irow];
    const int* adj_row = adj + (size_t)(ibl + irow) * NN + jb;
    const float* edp = e_dst + jb;

    const int cb   = wid * 32;                // wave's 32-col block
    const int arow = lane & 15;               // frag row (A) / col (B,D)
    const int kg8  = (lane >> 4) * 8;         // frag k-chunk
    // B-frag source: lane reads hT[cb + q*16 + arow][jb + jtile + kg8], 16B
    const short* hB = hT + (size_t)(cb + arow) * NN + jb + kg8;

    float dsum = 0.f;
    f32x4 acc00 = {0.f,0.f,0.f,0.f}, acc01 = acc00, acc10 = acc00, acc11 = acc00;

    // 2-deep prefetch: set A = even steps, set B = odd steps
    int2   adA = *(const int2*)(adj_row + jc2);
    float2 edA = *(const float2*)(edp + jc2);
    int4   b0A = *(const int4*)(hB);
    int4   b1A = *(const int4*)(hB + 16 * NN);
    int2   adB = *(const int2*)(adj_row + 32 + jc2);
    float2 edB = *(const float2*)(edp + 32 + jc2);
    int4   b0B = *(const int4*)(hB + 32);
    int4   b1B = *(const int4*)(hB + 16 * NN + 32);

#define MAIN_STEP(AD, ED, B0, B1, n)                                           \
    {                                                                          \
        const int c = (n) & 1;                                                 \
        int4 g0 = B0, g1 = B1;              /* current-step B frags */         \
        float s0 = es + ED.x, s1 = es + ED.y;                                  \
        float l0 = s0 > 0.f ? s0 : 0.01f * s0;                                 \
        float l1 = s1 > 0.f ? s1 : 0.01f * s1;                                 \
        float w0 = AD.x > 0 ? __expf(l0) : 0.f;                                \
        float w1 = AD.y > 0 ? __expf(l1) : 0.f;                                \
        short b0 = f2bf(w0), b1 = f2bf(w1);                                    \
        dsum += bf2f(b0) + bf2f(b1);    /* denom = SAME bf16-rounded weights */\
        *(unsigned*)&w_s[c][irow][jc2] =                                       \
            (unsigned)(unsigned short)b0 | ((unsigned)(unsigned short)b1 << 16);\
        int jn = (((n) + 2) & (NSTEP - 1)) * 32;    /* prefetch 2 ahead */     \
        AD = *(const int2*)(adj_row + jn + jc2);                               \
        ED = *(const float2*)(edp + jn + jc2);                                 \
        B0 = *(const int4*)(hB + jn);                                          \
        B1 = *(const int4*)(hB + 16 * NN + jn);                                \
        barrier_keep_vmem();          /* NO vmcnt drain: prefetch stays live */\
        short8 a0 = *(const short8*)&w_s[c][arow][kg8];                        \
        short8 a1 = *(const short8*)&w_s[c][16 + arow][kg8];                   \
        acc00 = __builtin_amdgcn_mfma_f32_16x16x32_bf16(a0, *(short8*)&g0, acc00, 0, 0, 0);\
        acc01 = __builtin_amdgcn_mfma_f32_16x16x32_bf16(a0, *(short8*)&g1, acc01, 0, 0, 0);\
        acc10 = __builtin_amdgcn_mfma_f32_16x16x32_bf16(a1, *(short8*)&g0, acc10, 0, 0, 0);\
        acc11 = __builtin_amdgcn_mfma_f32_16x16x32_bf16(a1, *(short8*)&g1, acc11, 0, 0, 0);\
    }

    for (int n = 0; n < NSTEP; n += 2) {
        MAIN_STEP(adA, edA, b0A, b1A, n)
        MAIN_STEP(adB, edB, b0B, b1B, n + 1)
    }
#undef MAIN_STEP

    // partial denom: 16 threads per row -> shfl tree, one writer per row
    dsum += __shfl_xor(dsum, 1);
    dsum += __shfl_xor(dsum, 2);
    dsum += __shfl_xor(dsum, 4);
    dsum += __shfl_xor(dsum, 8);
    if ((t & 15) == 0) den_part[half * NN + ibl + irow] = dsum;

    // write partial numerator: rows h*16 + (lane>>4)*4 + r, cols cb + q*16 + arow
    float* num = half ? num1 : num0;
    const int r4 = (lane >> 4) * 4;
    #pragma unroll
    for (int r = 0; r < 4; ++r) {
        size_t o0 = (size_t)(ibl + r4 + r) * DD + cb + arow;        // h=0
        size_t o1 = (size_t)(ibl + 16 + r4 + r) * DD + cb + arow;   // h=1
        num[o0]      = acc00[r];
        num[o0 + 16] = acc01[r];
        num[o1]      = acc10[r];
        num[o1 + 16] = acc11[r];
    }
}

// Kernel 3: out = elu((num0+num1) / (den0+den1)). num0 lives in d_out (in-place).
__global__ __launch_bounds__(256) void gat_epi(
    float* __restrict__ out, const float* __restrict__ num1,
    const float* __restrict__ den_part)
{
    int idx = blockIdx.x * 256 + threadIdx.x;       // float4 index; 64 per row
    int row = idx >> 6;
    float inv = 1.f / (den_part[row] + den_part[NN + row]);
    float4 p0 = ((const float4*)out)[idx];
    float4 p1 = ((const float4*)num1)[idx];
    float4 v;
    v.x = (p0.x + p1.x) * inv; v.x = v.x > 0.f ? v.x : expm1f(v.x);
    v.y = (p0.y + p1.y) * inv; v.y = v.y > 0.f ? v.y : expm1f(v.y);
    v.z = (p0.z + p1.z) * inv; v.z = v.z > 0.f ? v.z : expm1f(v.z);
    v.w = (p0.w + p1.w) * inv; v.w = v.w > 0.f ? v.w : expm1f(v.w);
    ((float4*)out)[idx] = v;
}

extern "C" void kernel_launch(void* const* d_in, const int* in_sizes, int n_in,
                              void* d_out, int out_size, void* d_ws, size_t ws_size,
                              hipStream_t stream) {
    const float* x   = (const float*)d_in[0];
    const int*   adj = (const int*)d_in[1];
    const float* W   = (const float*)d_in[2];
    const float* a   = (const float*)d_in[3];
    float* out = (float*)d_out;

    // ws layout: hT bf16 [256][8192] (4MB) | e_src | e_dst | den_part[2][NN] | num1 (8MB)
    char* w0 = (char*)d_ws;
    short* hT   = (short*)w0;
    float* esrc = (float*)(w0 + (size_t)DD * NN * 2);
    float* edst = esrc + NN;
    float* den  = edst + NN;
    float* num1 = den + 2 * NN;

    gat_prep<<<dim3(NN / 32), dim3(256), 0, stream>>>(x, W, a, hT, esrc, edst);
    gat_main<<<dim3((NN / 32) * JSPLIT), dim3(512), 0, stream>>>(
        adj, hT, esrc, edst, out, num1, den);
    gat_epi<<<dim3(NN * DD / 4 / 256), dim3(256), 0, stream>>>(out, num1, den);
}

// Round 6
// 221.271 us; speedup vs baseline: 1.0184x; 1.0184x over previous
//
#include <hip/hip_runtime.h>

#define NN 8192
#define DD 256
#define NSTEP (NN / 32)            // 256 K-steps per block (full j range)

typedef __attribute__((ext_vector_type(8))) short short8;   // 8 bf16 (4 VGPR) MFMA frag
typedef __attribute__((ext_vector_type(4))) float f32x4;    // MFMA accumulator

__device__ __forceinline__ short f2bf(float x) {
    union { float f; unsigned u; } v; v.f = x;
    unsigned r = (v.u + 0x7FFFu + ((v.u >> 16) & 1u)) >> 16;  // RNE
    return (short)r;
}
__device__ __forceinline__ float bf2f(short b) {
    union { float f; unsigned u; } v; v.u = ((unsigned)(unsigned short)b) << 16;
    return v.f;
}

// Barrier that does NOT drain vmcnt (in-flight global prefetch survives).
__device__ __forceinline__ void barrier_keep_vmem() {
    asm volatile("s_waitcnt lgkmcnt(0)" ::: "memory");
    __builtin_amdgcn_s_barrier();
    asm volatile("" ::: "memory");
}

// Kernel 0: bit-pack adj. adj [NN][NN] int32 -> bits [NN][NN/32] uint32.
// This is THE single streaming read of adj (256MB @ HBM BW); gat_main then
// works from the 8MB L2-resident bitmask. Bit j%32 of word j/32 = adj>0.
__global__ __launch_bounds__(256) void gat_pack(
    const int* __restrict__ adj, unsigned* __restrict__ bits)
{
    const int t   = threadIdx.x;
    const int row = blockIdx.x;                 // 8192 blocks, one row each
    const int* ar = adj + (size_t)row * NN;
    unsigned* br  = bits + (size_t)row * (NN / 32);
    #pragma unroll
    for (int i = 0; i < 8; ++i) {
        int j0 = i * 1024 + t * 4;
        int4 v = *(const int4*)(ar + j0);
        unsigned nib = (v.x > 0 ? 1u : 0u) | (v.y > 0 ? 2u : 0u)
                     | (v.z > 0 ? 4u : 0u) | (v.w > 0 ? 8u : 0u);
        unsigned word = nib << ((t & 7) * 4);   // bit pos = j0 % 32
        word |= __shfl_xor((int)word, 1);
        word |= __shfl_xor((int)word, 2);
        word |= __shfl_xor((int)word, 4);
        if ((t & 7) == 0) br[i * 32 + (t >> 3)] = word;  // word idx = j0/32
    }
}

// Kernel 1: h = x@W (fp32); emit hT (bf16, [D][N]), e_src, e_dst.
__global__ __launch_bounds__(256) void gat_prep(
    const float* __restrict__ x, const float* __restrict__ W,
    const float* __restrict__ a,
    short* __restrict__ hT, float* __restrict__ e_src, float* __restrict__ e_dst)
{
    __shared__ float x_s[32][260];          // +4 pad
    __shared__ float W_s[2][16][256];       // 16-row W chunk, double-buffered
    const int t  = threadIdx.x;
    const int ib = blockIdx.x * 32;

    #pragma unroll
    for (int rep = 0; rep < 8; ++rep) {
        int fi = rep * 256 + t;
        int r  = fi >> 6;
        int c4 = (fi & 63) * 4;
        float4 v = *(const float4*)(x + (size_t)(ib + r) * DD + c4);
        *(float4*)&x_s[r][c4] = v;
    }
    float4 wp[4];
    #pragma unroll
    for (int q = 0; q < 4; ++q) {
        int fi = q * 256 + t;
        wp[q] = *(const float4*)(W + (size_t)(fi >> 6) * DD + (fi & 63) * 4);
    }
    barrier_keep_vmem();

    const int il = t >> 3;
    const int dg = (t & 7) * 4;
    f32x4 acc[8];
    #pragma unroll
    for (int m = 0; m < 8; ++m) acc[m] = (f32x4){0.f, 0.f, 0.f, 0.f};

    for (int kc = 0; kc < 16; ++kc) {
        const int b = kc & 1;
        #pragma unroll
        for (int q = 0; q < 4; ++q) {
            int fi = q * 256 + t;
            *(float4*)&W_s[b][fi >> 6][(fi & 63) * 4] = wp[q];
        }
        if (kc < 15) {
            #pragma unroll
            for (int q = 0; q < 4; ++q) {
                int fi = q * 256 + t;
                wp[q] = *(const float4*)(W + (size_t)((kc + 1) * 16 + (fi >> 6)) * DD + (fi & 63) * 4);
            }
        }
        barrier_keep_vmem();
        #pragma unroll
        for (int kl = 0; kl < 16; ++kl) {
            float xv = x_s[il][kc * 16 + kl];
            #pragma unroll
            for (int m = 0; m < 8; ++m) {
                float4 wv = *(const float4*)&W_s[b][kl][m * 32 + dg];
                acc[m].x += xv * wv.x; acc[m].y += xv * wv.y;
                acc[m].z += xv * wv.z; acc[m].w += xv * wv.w;
            }
        }
    }

    const int ig = ib + il;
    float p1 = 0.f, p2 = 0.f;
    #pragma unroll
    for (int m = 0; m < 8; ++m) {
        #pragma unroll
        for (int j = 0; j < 4; ++j) {
            int col = m * 32 + dg + j;
            float hv = acc[m][j];
            p1 += hv * a[col];
            p2 += hv * a[DD + col];
            hT[(size_t)col * NN + ig] = f2bf(hv);
        }
    }
    p1 += __shfl_xor(p1, 1); p1 += __shfl_xor(p1, 2); p1 += __shfl_xor(p1, 4);
    p2 += __shfl_xor(p2, 1); p2 += __shfl_xor(p2, 2); p2 += __shfl_xor(p2, 4);
    if ((t & 7) == 0) { e_src[ig] = p1; e_dst[ig] = p2; }
}

// Kernel 2: fused masked softmax + attention@h, bitmask edition.
// 256 blocks x 32 rows, full j range (no split); all loop reads L2-resident
// (bits 8MB + hT 4MB + e_dst 32KB). Wave w owns cols [w*32,+32), both row
// halves: acc[2][2]. Denominator + ELU fused in-kernel (no epilogue pass).
__global__ __launch_bounds__(512) void gat_main(
    const unsigned* __restrict__ bits, const short* __restrict__ hT,
    const float* __restrict__ e_src, const float* __restrict__ e_dst,
    float* __restrict__ out)
{
    __shared__ __align__(16) short w_s[2][32][40];    // weight tile bf16 (only LDS)
    __shared__ float denom_s[32];

    const int t    = threadIdx.x;
    const int lane = t & 63;
    const int wid  = t >> 6;
    const int ibl  = blockIdx.x * 32;

    const int irow = t >> 4;                  // 0..31 (weight-builder row)
    const int jc2  = (t & 15) * 2;
    const float es = e_src[ibl + irow];
    const unsigned* bits_row = bits + (size_t)(ibl + irow) * (NN / 32);

    const int cb   = wid * 32;                // wave's 32-col block
    const int arow = lane & 15;               // frag row (A) / col (B,D)
    const int kg8  = (lane >> 4) * 8;         // frag k-chunk
    const short* hB = hT + (size_t)(cb + arow) * NN + kg8;

    float dsum = 0.f;
    f32x4 acc00 = {0.f,0.f,0.f,0.f}, acc01 = acc00, acc10 = acc00, acc11 = acc00;

    // 2-deep prefetch: set A = even steps, set B = odd steps
    unsigned bwA = bits_row[0];
    float2   edA = *(const float2*)(e_dst + jc2);
    int4     b0A = *(const int4*)(hB);
    int4     b1A = *(const int4*)(hB + 16 * NN);
    unsigned bwB = bits_row[1];
    float2   edB = *(const float2*)(e_dst + 32 + jc2);
    int4     b0B = *(const int4*)(hB + 32);
    int4     b1B = *(const int4*)(hB + 16 * NN + 32);

#define MAIN_STEP(BW, ED, B0, B1, n)                                           \
    {                                                                          \
        const int c = (n) & 1;                                                 \
        int4 g0 = B0, g1 = B1;              /* current-step B frags */         \
        float s0 = es + ED.x, s1 = es + ED.y;                                  \
        float l0 = s0 > 0.f ? s0 : 0.01f * s0;                                 \
        float l1 = s1 > 0.f ? s1 : 0.01f * s1;                                 \
        float w0 = ((BW >> jc2) & 1u)       ? __expf(l0) : 0.f;                \
        float w1 = ((BW >> (jc2 + 1)) & 1u) ? __expf(l1) : 0.f;                \
        short b0 = f2bf(w0), b1 = f2bf(w1);                                    \
        dsum += bf2f(b0) + bf2f(b1);    /* denom = SAME bf16-rounded weights */\
        *(unsigned*)&w_s[c][irow][jc2] =                                       \
            (unsigned)(unsigned short)b0 | ((unsigned)(unsigned short)b1 << 16);\
        int jn = (((n) + 2) & (NSTEP - 1)) * 32;    /* prefetch 2 ahead */     \
        BW = bits_row[jn >> 5];                                                \
        ED = *(const float2*)(e_dst + jn + jc2);                               \
        B0 = *(const int4*)(hB + jn);                                          \
        B1 = *(const int4*)(hB + 16 * NN + jn);                                \
        barrier_keep_vmem();          /* NO vmcnt drain: prefetch stays live */\
        short8 a0 = *(const short8*)&w_s[c][arow][kg8];                        \
        short8 a1 = *(const short8*)&w_s[c][16 + arow][kg8];                   \
        acc00 = __builtin_amdgcn_mfma_f32_16x16x32_bf16(a0, *(short8*)&g0, acc00, 0, 0, 0);\
        acc01 = __builtin_amdgcn_mfma_f32_16x16x32_bf16(a0, *(short8*)&g1, acc01, 0, 0, 0);\
        acc10 = __builtin_amdgcn_mfma_f32_16x16x32_bf16(a1, *(short8*)&g0, acc10, 0, 0, 0);\
        acc11 = __builtin_amdgcn_mfma_f32_16x16x32_bf16(a1, *(short8*)&g1, acc11, 0, 0, 0);\
    }

    for (int n = 0; n < NSTEP; n += 2) {
        MAIN_STEP(bwA, edA, b0A, b1A, n)
        MAIN_STEP(bwB, edB, b0B, b1B, n + 1)
    }
#undef MAIN_STEP

    // denom: 16 threads per row -> shfl tree, one writer per row
    dsum += __shfl_xor(dsum, 1);
    dsum += __shfl_xor(dsum, 2);
    dsum += __shfl_xor(dsum, 4);
    dsum += __shfl_xor(dsum, 8);
    if ((t & 15) == 0) denom_s[irow] = dsum;
    __syncthreads();

    // epilogue: out = elu(acc / denom). D-frag row = h*16 + (lane>>4)*4 + r,
    // col = cb + q*16 + arow.
    const int r4 = (lane >> 4) * 4;
    #pragma unroll
    for (int r = 0; r < 4; ++r) {
        float inv0 = 1.f / denom_s[r4 + r];
        float inv1 = 1.f / denom_s[16 + r4 + r];
        size_t o0 = (size_t)(ibl + r4 + r) * DD + cb + arow;        // h=0
        size_t o1 = (size_t)(ibl + 16 + r4 + r) * DD + cb + arow;   // h=1
        float v00 = acc00[r] * inv0; v00 = v00 > 0.f ? v00 : expm1f(v00);
        float v01 = acc01[r] * inv0; v01 = v01 > 0.f ? v01 : expm1f(v01);
        float v10 = acc10[r] * inv1; v10 = v10 > 0.f ? v10 : expm1f(v10);
        float v11 = acc11[r] * inv1; v11 = v11 > 0.f ? v11 : expm1f(v11);
        out[o0]      = v00;
        out[o0 + 16] = v01;
        out[o1]      = v10;
        out[o1 + 16] = v11;
    }
}

extern "C" void kernel_launch(void* const* d_in, const int* in_sizes, int n_in,
                              void* d_out, int out_size, void* d_ws, size_t ws_size,
                              hipStream_t stream) {
    const float* x   = (const float*)d_in[0];
    const int*   adj = (const int*)d_in[1];
    const float* W   = (const float*)d_in[2];
    const float* a   = (const float*)d_in[3];
    float* out = (float*)d_out;

    // ws layout: hT bf16 [256][8192] (4MB) | e_src | e_dst | bits (8MB) = 12.07MB
    char* w0 = (char*)d_ws;
    short* hT      = (short*)w0;
    float* esrc    = (float*)(w0 + (size_t)DD * NN * 2);
    float* edst    = esrc + NN;
    unsigned* bits = (unsigned*)(edst + NN);

    gat_pack<<<dim3(NN), dim3(256), 0, stream>>>(adj, bits);
    gat_prep<<<dim3(NN / 32), dim3(256), 0, stream>>>(x, W, a, hT, esrc, edst);
    gat_main<<<dim3(NN / 32), dim3(512), 0, stream>>>(bits, hT, esrc, edst, out);
}

// Round 7
// 216.381 us; speedup vs baseline: 1.0414x; 1.0226x over previous
//
#include <hip/hip_runtime.h>

#define NN 8192
#define DD 256

typedef __attribute__((ext_vector_type(8))) short short8;   // 8 bf16 (4 VGPR) MFMA frag
typedef __attribute__((ext_vector_type(4))) float f32x4;    // MFMA accumulator

__device__ __forceinline__ short f2bf(float x) {
    union { float f; unsigned u; } v; v.f = x;
    unsigned r = (v.u + 0x7FFFu + ((v.u >> 16) & 1u)) >> 16;  // RNE
    return (short)r;
}
__device__ __forceinline__ float bf2f(short b) {
    union { float f; unsigned u; } v; v.u = ((unsigned)(unsigned short)b) << 16;
    return v.f;
}

// Barrier that does NOT drain vmcnt (in-flight global prefetch survives).
__device__ __forceinline__ void barrier_keep_vmem() {
    asm volatile("s_waitcnt lgkmcnt(0)" ::: "memory");
    __builtin_amdgcn_s_barrier();
    asm volatile("" ::: "memory");
}

// Kernel 0: bit-pack adj. adj [NN][NN] int32 -> bits [NN][NN/32] uint32.
// This is THE single streaming read of adj (256MB @ HBM BW).
__global__ __launch_bounds__(256) void gat_pack(
    const int* __restrict__ adj, unsigned* __restrict__ bits)
{
    const int t   = threadIdx.x;
    const int row = blockIdx.x;                 // 8192 blocks, one row each
    const int* ar = adj + (size_t)row * NN;
    unsigned* br  = bits + (size_t)row * (NN / 32);
    #pragma unroll
    for (int i = 0; i < 8; ++i) {
        int j0 = i * 1024 + t * 4;
        int4 v = *(const int4*)(ar + j0);
        unsigned nib = (v.x > 0 ? 1u : 0u) | (v.y > 0 ? 2u : 0u)
                     | (v.z > 0 ? 4u : 0u) | (v.w > 0 ? 8u : 0u);
        unsigned word = nib << ((t & 7) * 4);   // bit pos = j0 % 32
        word |= __shfl_xor((int)word, 1);
        word |= __shfl_xor((int)word, 2);
        word |= __shfl_xor((int)word, 4);
        if ((t & 7) == 0) br[i * 32 + (t >> 3)] = word;  // word idx = j0/32
    }
}

// Kernel 1: h = x@W (fp32); emit hT (bf16, [D][N]), e_src, e_dst.
__global__ __launch_bounds__(256) void gat_prep(
    const float* __restrict__ x, const float* __restrict__ W,
    const float* __restrict__ a,
    short* __restrict__ hT, float* __restrict__ e_src, float* __restrict__ e_dst)
{
    __shared__ float x_s[32][260];          // +4 pad
    __shared__ float W_s[2][16][256];       // 16-row W chunk, double-buffered
    const int t  = threadIdx.x;
    const int ib = blockIdx.x * 32;

    #pragma unroll
    for (int rep = 0; rep < 8; ++rep) {
        int fi = rep * 256 + t;
        int r  = fi >> 6;
        int c4 = (fi & 63) * 4;
        float4 v = *(const float4*)(x + (size_t)(ib + r) * DD + c4);
        *(float4*)&x_s[r][c4] = v;
    }
    float4 wp[4];
    #pragma unroll
    for (int q = 0; q < 4; ++q) {
        int fi = q * 256 + t;
        wp[q] = *(const float4*)(W + (size_t)(fi >> 6) * DD + (fi & 63) * 4);
    }
    barrier_keep_vmem();

    const int il = t >> 3;
    const int dg = (t & 7) * 4;
    f32x4 acc[8];
    #pragma unroll
    for (int m = 0; m < 8; ++m) acc[m] = (f32x4){0.f, 0.f, 0.f, 0.f};

    for (int kc = 0; kc < 16; ++kc) {
        const int b = kc & 1;
        #pragma unroll
        for (int q = 0; q < 4; ++q) {
            int fi = q * 256 + t;
            *(float4*)&W_s[b][fi >> 6][(fi & 63) * 4] = wp[q];
        }
        if (kc < 15) {
            #pragma unroll
            for (int q = 0; q < 4; ++q) {
                int fi = q * 256 + t;
                wp[q] = *(const float4*)(W + (size_t)((kc + 1) * 16 + (fi >> 6)) * DD + (fi & 63) * 4);
            }
        }
        barrier_keep_vmem();
        #pragma unroll
        for (int kl = 0; kl < 16; ++kl) {
            float xv = x_s[il][kc * 16 + kl];
            #pragma unroll
            for (int m = 0; m < 8; ++m) {
                float4 wv = *(const float4*)&W_s[b][kl][m * 32 + dg];
                acc[m].x += xv * wv.x; acc[m].y += xv * wv.y;
                acc[m].z += xv * wv.z; acc[m].w += xv * wv.w;
            }
        }
    }

    const int ig = ib + il;
    float p1 = 0.f, p2 = 0.f;
    #pragma unroll
    for (int m = 0; m < 8; ++m) {
        #pragma unroll
        for (int j = 0; j < 4; ++j) {
            int col = m * 32 + dg + j;
            float hv = acc[m][j];
            p1 += hv * a[col];
            p2 += hv * a[DD + col];
            hT[(size_t)col * NN + ig] = f2bf(hv);
        }
    }
    p1 += __shfl_xor(p1, 1); p1 += __shfl_xor(p1, 2); p1 += __shfl_xor(p1, 4);
    p2 += __shfl_xor(p2, 1); p2 += __shfl_xor(p2, 2); p2 += __shfl_xor(p2, 4);
    if ((t & 7) == 0) { e_src[ig] = p1; e_dst[ig] = p2; }
}

// Kernel 2: barrier-free wave-autonomous fused masked-softmax GEMM.
// Block = 32 rows; wave w owns j-chunk [w*1024,(w+1)*1024) = 32 tiles of 32 j.
// Each lane builds its OWN A-frag weights in-register (rows lane&15 and +16,
// j = kg8..kg8+8) and accumulates partial numerators for ALL 256 cols:
// acc0/acc1[16] f32x4. Main loop: 0 barriers, 0 LDS. Epilogue: LDS exchange
// sums 8 waves' partials + denoms, applies 1/den + ELU.
__global__ __launch_bounds__(512, 2) void gat_main(
    const unsigned* __restrict__ bits, const short* __restrict__ hT,
    const float* __restrict__ e_src, const float* __restrict__ e_dst,
    float* __restrict__ out)
{
    __shared__ float xch[8][32][132];   // 135 KB partial-numerator exchange (+4 pad)
    __shared__ float denw[8][32];       // per-wave partial denominators

    const int t    = threadIdx.x;
    const int lane = t & 63;
    const int w    = t >> 6;            // wave id = j-chunk id
    const int ibl  = blockIdx.x * 32;

    const int arow = lane & 15;
    const int kg8  = (lane >> 4) * 8;
    const int jw   = w * (NN / 8);      // wave's j base (1024 j's)

    const float es0 = e_src[ibl + arow];
    const float es1 = e_src[ibl + 16 + arow];
    const unsigned* br0 = bits + (size_t)(ibl + arow) * (NN / 32) + (jw >> 5);
    const unsigned* br1 = br0 + 16 * (NN / 32);
    const float* edp = e_dst + jw + kg8;
    const short* hB  = hT + (size_t)arow * NN + jw + kg8;

    f32x4 acc0[16], acc1[16];
    #pragma unroll
    for (int q = 0; q < 16; ++q) {
        acc0[q] = (f32x4){0.f, 0.f, 0.f, 0.f};
        acc1[q] = (f32x4){0.f, 0.f, 0.f, 0.f};
    }
    float dsum0 = 0.f, dsum1 = 0.f;

    #pragma unroll 2
    for (int n = 0; n < 32; ++n) {
        const int j32 = n * 32;
        // issue first half of B-frag loads + scalars (L2-resident)
        unsigned bw0 = br0[n];
        unsigned bw1 = br1[n];
        float4 e0 = *(const float4*)(edp + j32);
        float4 e1 = *(const float4*)(edp + j32 + 4);
        int4 bq0[8], bq1[8];
        #pragma unroll
        for (int q = 0; q < 8; ++q)
            bq0[q] = *(const int4*)(hB + (size_t)q * 16 * NN + j32);

        // build A-frags in-register (overlaps the in-flight loads)
        short8 af0, af1;
        float ed[8] = {e0.x, e0.y, e0.z, e0.w, e1.x, e1.y, e1.z, e1.w};
        #pragma unroll
        for (int i = 0; i < 8; ++i) {
            float s0 = es0 + ed[i], s1 = es1 + ed[i];
            float l0 = s0 > 0.f ? s0 : 0.01f * s0;
            float l1 = s1 > 0.f ? s1 : 0.01f * s1;
            float w0 = ((bw0 >> (kg8 + i)) & 1u) ? __expf(l0) : 0.f;
            float w1 = ((bw1 >> (kg8 + i)) & 1u) ? __expf(l1) : 0.f;
            short b0 = f2bf(w0), b1 = f2bf(w1);
            af0[i] = b0; af1[i] = b1;
            dsum0 += bf2f(b0);          // denom = SAME bf16-rounded weights
            dsum1 += bf2f(b1);
        }

        // second half of B-frag loads
        #pragma unroll
        for (int q = 0; q < 8; ++q)
            bq1[q] = *(const int4*)(hB + (size_t)(8 + q) * 16 * NN + j32);

        #pragma unroll
        for (int q = 0; q < 8; ++q) {
            acc0[q] = __builtin_amdgcn_mfma_f32_16x16x32_bf16(af0, *(short8*)&bq0[q], acc0[q], 0, 0, 0);
            acc1[q] = __builtin_amdgcn_mfma_f32_16x16x32_bf16(af1, *(short8*)&bq0[q], acc1[q], 0, 0, 0);
        }
        #pragma unroll
        for (int q = 0; q < 8; ++q) {
            acc0[8 + q] = __builtin_amdgcn_mfma_f32_16x16x32_bf16(af0, *(short8*)&bq1[q], acc0[8 + q], 0, 0, 0);
            acc1[8 + q] = __builtin_amdgcn_mfma_f32_16x16x32_bf16(af1, *(short8*)&bq1[q], acc1[8 + q], 0, 0, 0);
        }
    }

    // per-wave denom: lanes {r, r+16, r+32, r+48} hold row r's 4 k-chunks
    dsum0 += __shfl_xor(dsum0, 16); dsum0 += __shfl_xor(dsum0, 32);
    dsum1 += __shfl_xor(dsum1, 16); dsum1 += __shfl_xor(dsum1, 32);
    if (lane < 16) { denw[w][lane] = dsum0; denw[w][16 + lane] = dsum1; }
    __syncthreads();

    // each lane's 8 output rows: rh*16 + orow + i
    const int ocol = lane & 15;
    const int orow = (lane >> 4) * 4;
    float inv[2][4];
    #pragma unroll
    for (int rh = 0; rh < 2; ++rh)
        #pragma unroll
        for (int i = 0; i < 4; ++i) {
            int row = rh * 16 + orow + i;
            float d = 0.f;
            #pragma unroll
            for (int sw = 0; sw < 8; ++sw) d += denw[sw][row];
            inv[rh][i] = 1.f / d;
        }

    // two-phase column exchange: phase p covers cols [p*128, p*128+128)
    #pragma unroll
    for (int p = 0; p < 2; ++p) {
        __syncthreads();                        // xch reuse safety
        #pragma unroll
        for (int q = 0; q < 8; ++q)
            #pragma unroll
            for (int i = 0; i < 4; ++i) {
                xch[w][orow + i][q * 16 + ocol]      = acc0[p * 8 + q][i];
                xch[w][16 + orow + i][q * 16 + ocol] = acc1[p * 8 + q][i];
            }
        __syncthreads();
        // wave w sums cols [w*16, w*16+16) of this phase across all 8 waves
        #pragma unroll
        for (int rh = 0; rh < 2; ++rh)
            #pragma unroll
            for (int i = 0; i < 4; ++i) {
                int row = rh * 16 + orow + i;
                float s = 0.f;
                #pragma unroll
                for (int sw = 0; sw < 8; ++sw) s += xch[sw][row][w * 16 + ocol];
                float v = s * inv[rh][i];
                v = v > 0.f ? v : expm1f(v);
                out[(size_t)(ibl + row) * DD + p * 128 + w * 16 + ocol] = v;
            }
    }
}

extern "C" void kernel_launch(void* const* d_in, const int* in_sizes, int n_in,
                              void* d_out, int out_size, void* d_ws, size_t ws_size,
                              hipStream_t stream) {
    const float* x   = (const float*)d_in[0];
    const int*   adj = (const int*)d_in[1];
    const float* W   = (const float*)d_in[2];
    const float* a   = (const float*)d_in[3];
    float* out = (float*)d_out;

    // ws layout: hT bf16 [256][8192] (4MB) | e_src | e_dst | bits (8MB) = 12.07MB
    char* w0 = (char*)d_ws;
    short* hT      = (short*)w0;
    float* esrc    = (float*)(w0 + (size_t)DD * NN * 2);
    float* edst    = esrc + NN;
    unsigned* bits = (unsigned*)(edst + NN);

    gat_pack<<<dim3(NN), dim3(256), 0, stream>>>(adj, bits);
    gat_prep<<<dim3(NN / 32), dim3(256), 0, stream>>>(x, W, a, hT, esrc, edst);
    gat_main<<<dim3(NN / 32), dim3(512), 0, stream>>>(bits, hT, esrc, edst, out);
}

// Round 8
// 211.410 us; speedup vs baseline: 1.0659x; 1.0235x over previous
//
#include <hip/hip_runtime.h>

#define NN 8192
#define DD 256
#define BM 256                 // rows per block
#define JSPLIT 8
#define JC (NN / JSPLIT)       // 1024 j's per block
#define NT (JC / 32)           // 32 tiles per block

typedef __attribute__((ext_vector_type(8))) short short8;   // 8 bf16 MFMA frag
typedef __attribute__((ext_vector_type(4))) float f32x4;    // MFMA accumulator

__device__ __forceinline__ short f2bf(float x) {
    union { float f; unsigned u; } v; v.f = x;
    unsigned r = (v.u + 0x7FFFu + ((v.u >> 16) & 1u)) >> 16;  // RNE
    return (short)r;
}
__device__ __forceinline__ float bf2f(short b) {
    union { float f; unsigned u; } v; v.u = ((unsigned)(unsigned short)b) << 16;
    return v.f;
}

// Barrier that does NOT drain vmcnt (in-flight global prefetch survives).
__device__ __forceinline__ void barrier_keep_vmem() {
    asm volatile("s_waitcnt lgkmcnt(0)" ::: "memory");
    __builtin_amdgcn_s_barrier();
    asm volatile("" ::: "memory");
}

// Kernel 0: bit-pack adj. adj [NN][NN] int32 -> bits [NN][NN/32] uint32.
// THE single streaming read of adj (256MB @ HBM BW = the hard floor).
__global__ __launch_bounds__(256) void gat_pack(
    const int* __restrict__ adj, unsigned* __restrict__ bits)
{
    const int t   = threadIdx.x;
    const int row = blockIdx.x;
    const int* ar = adj + (size_t)row * NN;
    unsigned* br  = bits + (size_t)row * (NN / 32);
    #pragma unroll
    for (int i = 0; i < 8; ++i) {
        int j0 = i * 1024 + t * 4;
        int4 v = *(const int4*)(ar + j0);
        unsigned nib = (v.x > 0 ? 1u : 0u) | (v.y > 0 ? 2u : 0u)
                     | (v.z > 0 ? 4u : 0u) | (v.w > 0 ? 8u : 0u);
        unsigned word = nib << ((t & 7) * 4);
        word |= __shfl_xor((int)word, 1);
        word |= __shfl_xor((int)word, 2);
        word |= __shfl_xor((int)word, 4);
        if ((t & 7) == 0) br[i * 32 + (t >> 3)] = word;
    }
}

// Kernel 1: h = x@W (fp32); emit hT (bf16, [D][N]), e_src, e_dst.
__global__ __launch_bounds__(256) void gat_prep(
    const float* __restrict__ x, const float* __restrict__ W,
    const float* __restrict__ a,
    short* __restrict__ hT, float* __restrict__ e_src, float* __restrict__ e_dst)
{
    __shared__ float x_s[32][260];          // +4 pad
    __shared__ float W_s[2][16][256];       // 16-row W chunk, double-buffered
    const int t  = threadIdx.x;
    const int ib = blockIdx.x * 32;

    #pragma unroll
    for (int rep = 0; rep < 8; ++rep) {
        int fi = rep * 256 + t;
        int r  = fi >> 6;
        int c4 = (fi & 63) * 4;
        float4 v = *(const float4*)(x + (size_t)(ib + r) * DD + c4);
        *(float4*)&x_s[r][c4] = v;
    }
    float4 wp[4];
    #pragma unroll
    for (int q = 0; q < 4; ++q) {
        int fi = q * 256 + t;
        wp[q] = *(const float4*)(W + (size_t)(fi >> 6) * DD + (fi & 63) * 4);
    }
    barrier_keep_vmem();

    const int il = t >> 3;
    const int dg = (t & 7) * 4;
    f32x4 acc[8];
    #pragma unroll
    for (int m = 0; m < 8; ++m) acc[m] = (f32x4){0.f, 0.f, 0.f, 0.f};

    for (int kc = 0; kc < 16; ++kc) {
        const int b = kc & 1;
        #pragma unroll
        for (int q = 0; q < 4; ++q) {
            int fi = q * 256 + t;
            *(float4*)&W_s[b][fi >> 6][(fi & 63) * 4] = wp[q];
        }
        if (kc < 15) {
            #pragma unroll
            for (int q = 0; q < 4; ++q) {
                int fi = q * 256 + t;
                wp[q] = *(const float4*)(W + (size_t)((kc + 1) * 16 + (fi >> 6)) * DD + (fi & 63) * 4);
            }
        }
        barrier_keep_vmem();
        #pragma unroll
        for (int kl = 0; kl < 16; ++kl) {
            float xv = x_s[il][kc * 16 + kl];
            #pragma unroll
            for (int m = 0; m < 8; ++m) {
                float4 wv = *(const float4*)&W_s[b][kl][m * 32 + dg];
                acc[m].x += xv * wv.x; acc[m].y += xv * wv.y;
                acc[m].z += xv * wv.z; acc[m].w += xv * wv.w;
            }
        }
    }

    const int ig = ib + il;
    float p1 = 0.f, p2 = 0.f;
    #pragma unroll
    for (int m = 0; m < 8; ++m) {
        #pragma unroll
        for (int j = 0; j < 4; ++j) {
            int col = m * 32 + dg + j;
            float hv = acc[m][j];
            p1 += hv * a[col];
            p2 += hv * a[DD + col];
            hT[(size_t)col * NN + ig] = f2bf(hv);
        }
    }
    p1 += __shfl_xor(p1, 1); p1 += __shfl_xor(p1, 2); p1 += __shfl_xor(p1, 4);
    p2 += __shfl_xor(p2, 1); p2 += __shfl_xor(p2, 2); p2 += __shfl_xor(p2, 4);
    if ((t & 7) == 0) { e_src[ig] = p1; e_dst[ig] = p2; }
}

// Kernel 2: barrier-free fused masked-softmax partial GEMM, BM=256 x JC=1024.
// Block (rb = bid>>3, jc = bid&7): rows [rb*256,+256), j in [jc*1024,+1024).
// jc = bid&7 -> round-robin dispatch keeps one j-chunk per XCD: the 512KB hT
// window is XCD-L2 resident. Wave w = (rowq=w&3, colh=w>>2): 64 rows x 128
// cols, 4 A-frags x 8 B-frags -> 32 MFMA/tile with 4x B-frag reuse.
// Main loop: 0 barriers, 0 LDS. Writes fp32 partial numerator + denom.
__global__ __launch_bounds__(512, 2) void gat_main(
    const unsigned* __restrict__ bits, const short* __restrict__ hT,
    const float* __restrict__ e_src, const float* __restrict__ e_dst,
    float* __restrict__ num, float* __restrict__ den_part)
{
    const int t    = threadIdx.x;
    const int lane = t & 63;
    const int w    = t >> 6;
    const int jc   = blockIdx.x & (JSPLIT - 1);
    const int rb   = blockIdx.x >> 3;
    const int jbase = jc * JC;
    const int rowq = w & 3;
    const int colh = w >> 2;
    const int arow = lane & 15;
    const int kg8  = (lane >> 4) * 8;
    const int rbase = rb * BM + rowq * 64;

    float es[4];
    const unsigned* brp[4];
    #pragma unroll
    for (int rt = 0; rt < 4; ++rt) {
        es[rt]  = e_src[rbase + rt * 16 + arow];
        brp[rt] = bits + (size_t)(rbase + rt * 16 + arow) * (NN / 32) + (jbase >> 5);
    }
    const float* edp = e_dst + jbase + kg8;
    const short* hB  = hT + (size_t)(colh * 128 + arow) * NN + jbase + kg8;

    f32x4 acc[4][8];
    #pragma unroll
    for (int rt = 0; rt < 4; ++rt)
        #pragma unroll
        for (int q = 0; q < 8; ++q) acc[rt][q] = (f32x4){0.f, 0.f, 0.f, 0.f};
    float ds[4] = {0.f, 0.f, 0.f, 0.f};

    // prefetched mask words + e_dst for tile 0
    unsigned bw[4];
    #pragma unroll
    for (int rt = 0; rt < 4; ++rt) bw[rt] = brp[rt][0];
    float4 e0 = *(const float4*)(edp);
    float4 e1 = *(const float4*)(edp + 4);

    for (int n = 0; n < NT; ++n) {
        const int j32 = n * 32;
        // issue all 8 B-frag loads (XCD-L2 resident); A-build below covers them
        int4 bq[8];
        #pragma unroll
        for (int q = 0; q < 8; ++q)
            bq[q] = *(const int4*)(hB + (size_t)q * 16 * NN + j32);

        float ed[8] = {e0.x, e0.y, e0.z, e0.w, e1.x, e1.y, e1.z, e1.w};
        short8 af[4];
        #pragma unroll
        for (int rt = 0; rt < 4; ++rt) {
            #pragma unroll
            for (int i = 0; i < 8; ++i) {
                float s = es[rt] + ed[i];
                float l = s > 0.f ? s : 0.01f * s;
                float wv = ((bw[rt] >> (kg8 + i)) & 1u) ? __expf(l) : 0.f;
                short b = f2bf(wv);
                af[rt][i] = b;
                ds[rt] += bf2f(b);      // denom = SAME bf16-rounded weights
            }
        }
        if (n + 1 < NT) {               // prefetch next tile's mask + e_dst
            #pragma unroll
            for (int rt = 0; rt < 4; ++rt) bw[rt] = brp[rt][n + 1];
            e0 = *(const float4*)(edp + j32 + 32);
            e1 = *(const float4*)(edp + j32 + 36);
        }
        #pragma unroll
        for (int rt = 0; rt < 4; ++rt)
            #pragma unroll
            for (int q = 0; q < 8; ++q)
                acc[rt][q] = __builtin_amdgcn_mfma_f32_16x16x32_bf16(
                    af[rt], *(short8*)&bq[q], acc[rt][q], 0, 0, 0);
    }

    // partial denom: reduce kg8 groups; colh==0 wave writes (colh==1 identical)
    #pragma unroll
    for (int rt = 0; rt < 4; ++rt) {
        float d = ds[rt];
        d += __shfl_xor(d, 16);
        d += __shfl_xor(d, 32);
        if (colh == 0 && lane < 16)
            den_part[(size_t)jc * NN + rbase + rt * 16 + lane] = d;
    }

    // partial numerator: row = rbase + rt*16 + (lane>>4)*4 + r, col = colh*128 + q*16 + arow
    float* np = num + (size_t)jc * NN * DD;
    const int r4 = (lane >> 4) * 4;
    #pragma unroll
    for (int rt = 0; rt < 4; ++rt)
        #pragma unroll
        for (int q = 0; q < 8; ++q) {
            size_t o = (size_t)(rbase + rt * 16 + r4) * DD + colh * 128 + q * 16 + arow;
            #pragma unroll
            for (int r = 0; r < 4; ++r)
                np[o + (size_t)r * DD] = acc[rt][q][r];
        }
}

// Kernel 3: out = elu( (sum_p num[p]) / (sum_p den[p]) ). Streaming, 72MB.
__global__ __launch_bounds__(256) void gat_epi(
    float* __restrict__ out, const float* __restrict__ num,
    const float* __restrict__ den_part)
{
    int idx = blockIdx.x * 256 + threadIdx.x;       // float4 index; 64 per row
    int row = idx >> 6;
    float d = 0.f;
    #pragma unroll
    for (int p = 0; p < JSPLIT; ++p) d += den_part[(size_t)p * NN + row];
    float4 s = {0.f, 0.f, 0.f, 0.f};
    #pragma unroll
    for (int p = 0; p < JSPLIT; ++p) {
        float4 v = ((const float4*)(num + (size_t)p * NN * DD))[idx];
        s.x += v.x; s.y += v.y; s.z += v.z; s.w += v.w;
    }
    float inv = 1.f / d;
    float4 o;
    o.x = s.x * inv; o.x = o.x > 0.f ? o.x : expm1f(o.x);
    o.y = s.y * inv; o.y = o.y > 0.f ? o.y : expm1f(o.y);
    o.z = s.z * inv; o.z = o.z > 0.f ? o.z : expm1f(o.z);
    o.w = s.w * inv; o.w = o.w > 0.f ? o.w : expm1f(o.w);
    ((float4*)out)[idx] = o;
}

extern "C" void kernel_launch(void* const* d_in, const int* in_sizes, int n_in,
                              void* d_out, int out_size, void* d_ws, size_t ws_size,
                              hipStream_t stream) {
    const float* x   = (const float*)d_in[0];
    const int*   adj = (const int*)d_in[1];
    const float* W   = (const float*)d_in[2];
    const float* a   = (const float*)d_in[3];
    float* out = (float*)d_out;

    // ws: hT 4MB | e_src 32KB | e_dst 32KB | bits 8MB | den 256KB | num 64MB
    char* w0 = (char*)d_ws;
    short* hT      = (short*)w0;
    float* esrc    = (float*)(w0 + (size_t)DD * NN * 2);
    float* edst    = esrc + NN;
    unsigned* bits = (unsigned*)(edst + NN);
    float* den     = (float*)((char*)bits + (size_t)NN * (NN / 32) * 4);
    float* num     = den + (size_t)JSPLIT * NN;

    gat_pack<<<dim3(NN), dim3(256), 0, stream>>>(adj, bits);
    gat_prep<<<dim3(NN / 32), dim3(256), 0, stream>>>(x, W, a, hT, esrc, edst);
    gat_main<<<dim3((NN / BM) * JSPLIT), dim3(512), 0, stream>>>(
        bits, hT, esrc, edst, num, den);
    gat_epi<<<dim3(NN * DD / 4 / 256), dim3(256), 0, stream>>>(out, num, den);
}